// Round 1
// baseline (298.946 us; speedup 1.0000x reference)
//
#include <hip/hip_runtime.h>
#include <math.h>

// NoisyTopKRouter: B=4, T=4096, C=2048, E=64, K=8; rows = 16384.
// (1) convert_w: split w into hi/lo bf16 packed in MFMA-fragment order.
// (2) router_fused: split-bf16 MFMA GEMM over FULL K per block (BM=32,
//     BK=64 staged, B frags direct from global / L2-resident, register
//     double-buffered at k-chunk depth), then in-block epilogue:
//     rank-by-counting top-8, sparse softmax, selective f64 near-tie
//     repair. Eliminates the 32 MB `part` round-trip + third launch.

#define CDIM  2048
#define EDIM  64
#define NOUT  128
#define TOPK  8
#define BM    32
#define BKS   64             // K floats staged per LDS buffer (2 MFMA chunks)
#define NSIT  (CDIM / BKS)   // 32 staging iterations
#define NKC   (CDIM / 32)    // 64 k-chunks of 32
#define TAU   1e-3f
#define XPS   136            // xsh pitch (shorts): hi[64] | lo[64] | pad 8

typedef __attribute__((ext_vector_type(8))) short bf16x8;
typedef __attribute__((ext_vector_type(4))) float f32x4;

__device__ __forceinline__ void split8(const float4 a, const float4 b,
                                       bf16x8& h8, bf16x8& l8) {
    const float vv[8] = {a.x, a.y, a.z, a.w, b.x, b.y, b.z, b.w};
    #pragma unroll
    for (int j = 0; j < 8; ++j) {
        const __bf16 h = (__bf16)vv[j];
        const __bf16 l = (__bf16)(vv[j] - (float)h);
        h8[j] = __builtin_bit_cast(short, h);
        l8[j] = __builtin_bit_cast(short, l);
    }
}

// ---- kernel 1: pack w into MFMA-fragment order, hi/lo bf16.
// slot s = (kc*8 + cg)*64 + lane holds w[col = cg*16 + (lane&15)]
//                                    [k = kc*32 + (lane>>4)*8 + j]
__global__ __launch_bounds__(256)
void convert_w(const float* __restrict__ wr, const float* __restrict__ wn,
               short* __restrict__ whi, short* __restrict__ wlo) {
    const int s    = (int)blockIdx.x * 256 + (int)threadIdx.x;  // 0..32767
    const int lane = s & 63;
    const int cg   = (s >> 6) & 7;
    const int kc   = s >> 9;
    const int col  = cg * 16 + (lane & 15);
    const int k0   = kc * 32 + (lane >> 4) * 8;
    const float* src = (col < EDIM ? wr + (size_t)col * CDIM
                                   : wn + (size_t)(col - EDIM) * CDIM) + k0;
    const float4 a = *(const float4*)src;
    const float4 b = *(const float4*)(src + 4);
    bf16x8 h8, l8; split8(a, b, h8, l8);
    *(bf16x8*)(whi + (size_t)s * 8) = h8;
    *(bf16x8*)(wlo + (size_t)s * 8) = l8;
}

// ---- kernel 2: fused full-K GEMM + top-k epilogue, one block = 32 rows
__global__ __launch_bounds__(256, 2)
void router_fused(const float* __restrict__ x,
                  const short* __restrict__ whi,
                  const short* __restrict__ wlo,
                  const float* __restrict__ w_route,
                  const float* __restrict__ w_noise,
                  const float* __restrict__ noise,
                  float* __restrict__ out_probs,
                  float* __restrict__ out_idx)
{
    __shared__ __align__(16) short xsh[2][BM][XPS];   // 17.0 KB
    __shared__ __align__(16) float scr[BM][NOUT + 8]; // 17.0 KB score tile
    __shared__ __align__(16) float vals[4][64];
    __shared__ __align__(16) float srt[4][64];

    const int tid  = (int)threadIdx.x;
    const int lane = tid & 63;
    const int wid  = tid >> 6;
    const int wr   = wid >> 1;          // row half (16 rows)
    const int wc   = wid & 1;           // col half (64 cols)
    const int l15  = lane & 15;
    const int q8   = (lane >> 4) * 8;
    const int q4   = (lane >> 4) * 4;
    const int row0 = (int)blockIdx.x * BM;

    const int srow = tid >> 3;          // 0..31
    const int skk  = (tid & 7) * 8;     // 0..56 (floats == shorts-in-chunk)
    const float* xsrc = x + (size_t)(row0 + srow) * CDIM + skk;

    f32x4 acc[4];
    #pragma unroll
    for (int nc = 0; nc < 4; ++nc)
        acc[nc] = (f32x4){0.f, 0.f, 0.f, 0.f};

    // B frags: register dbuf at k-chunk depth; bh[p] holds k-chunk (g0+p)
    bf16x8 bh[2][4], bl[2][4];
    auto loadB = [&](int buf, int kc) {
        const int base = (kc * 8 + wc * 4) * 512 + lane * 8;
        #pragma unroll
        for (int nc = 0; nc < 4; ++nc) {
            bh[buf][nc] = *(const bf16x8*)(whi + base + nc * 512);
            bl[buf][nc] = *(const bf16x8*)(wlo + base + nc * 512);
        }
    };

    // prologue: B(kc=0) + x-chunk(0)
    loadB(0, 0);
    {
        const float4 a = *(const float4*)xsrc;
        const float4 b = *(const float4*)(xsrc + 4);
        bf16x8 h8, l8; split8(a, b, h8, l8);
        *(bf16x8*)&xsh[0][srow][skk]      = h8;
        *(bf16x8*)&xsh[0][srow][64 + skk] = l8;
    }
    __syncthreads();

    #pragma unroll 2
    for (int sit = 0; sit < NSIT; ++sit) {
        const int  cur = sit & 1;
        const bool pf  = (sit + 1 < NSIT);
        const int  g0  = sit * 2;

        // issue B(g0+1) FIRST so its vmcnt wait (mid-sit) does not force
        // draining the later-issued HBM x loads (vmcnt is in-order).
        loadB(1, g0 + 1);
        float4 pa, pb;
        if (pf) {   // x for sit+1; consumed at end of this sit
            pa = *(const float4*)(xsrc + (sit + 1) * BKS);
            pb = *(const float4*)(xsrc + (sit + 1) * BKS + 4);
        }

        const short* ar = &xsh[cur][wr * 16 + l15][0];
        {   // k-chunk g0 (bh[0], loaded last sit / prologue)
            const bf16x8 ah = *(const bf16x8*)(ar + q8);
            const bf16x8 al = *(const bf16x8*)(ar + 64 + q8);
            #pragma unroll
            for (int nc = 0; nc < 4; ++nc) {
                acc[nc] = __builtin_amdgcn_mfma_f32_16x16x32_bf16(ah, bh[0][nc], acc[nc], 0, 0, 0);
                acc[nc] = __builtin_amdgcn_mfma_f32_16x16x32_bf16(al, bh[0][nc], acc[nc], 0, 0, 0);
                acc[nc] = __builtin_amdgcn_mfma_f32_16x16x32_bf16(ah, bl[0][nc], acc[nc], 0, 0, 0);
            }
        }
        if (g0 + 2 < NKC) loadB(0, g0 + 2);   // next sit's first k-chunk
        {   // k-chunk g0+1 (bh[1], loaded this sit)
            const bf16x8 ah = *(const bf16x8*)(ar + 32 + q8);
            const bf16x8 al = *(const bf16x8*)(ar + 96 + q8);
            #pragma unroll
            for (int nc = 0; nc < 4; ++nc) {
                acc[nc] = __builtin_amdgcn_mfma_f32_16x16x32_bf16(ah, bh[1][nc], acc[nc], 0, 0, 0);
                acc[nc] = __builtin_amdgcn_mfma_f32_16x16x32_bf16(al, bh[1][nc], acc[nc], 0, 0, 0);
                acc[nc] = __builtin_amdgcn_mfma_f32_16x16x32_bf16(ah, bl[1][nc], acc[nc], 0, 0, 0);
            }
        }
        if (pf) {   // x loads have had the whole MFMA phase to land
            bf16x8 h8, l8; split8(pa, pb, h8, l8);
            *(bf16x8*)&xsh[cur ^ 1][srow][skk]      = h8;
            *(bf16x8*)&xsh[cur ^ 1][srow][64 + skk] = l8;
        }
        __syncthreads();
    }

    // exchange scores through LDS (C/D layout: row = quad*4+reg, col = lane&15)
    #pragma unroll
    for (int nc = 0; nc < 4; ++nc)
        #pragma unroll
        for (int g = 0; g < 4; ++g)
            scr[wr * 16 + q4 + g][wc * 64 + nc * 16 + l15] = acc[nc][g];
    __syncthreads();

    // ---- per-row epilogue: wave = one row, 8 rows per wave
    #pragma unroll 1
    for (int r8 = 0; r8 < 8; ++r8) {
        const int row  = wid * 8 + r8;
        const int grow = row0 + row;

        const float route = scr[row][lane];
        const float nz    = scr[row][EDIM + lane];
        const float nv    = noise[(size_t)grow * EDIM + lane];
        const float sp = fmaxf(nz, 0.f) + log1pf(expf(-fabsf(nz)));
        const float nl = route + nv * sp;

        vals[wid][lane] = nl;
        __syncthreads();

        // rank = #{j better than me}; "better" = (v_j > v_i) or tie with j < i
        int cnt = 0;
        #pragma unroll
        for (int jq = 0; jq < 16; ++jq) {
            const float4 v = *(const float4*)&vals[wid][jq * 4];
            const int j0 = jq * 4;
            cnt += (v.x > nl || (v.x == nl && (j0 + 0) < lane));
            cnt += (v.y > nl || (v.y == nl && (j0 + 1) < lane));
            cnt += (v.z > nl || (v.z == nl && (j0 + 2) < lane));
            cnt += (v.w > nl || (v.w == nl && (j0 + 3) < lane));
        }
        srt[wid][cnt] = nl;   // ranks are a permutation of 0..63
        __syncthreads();

        const float m = srt[wid][0];
        // gap scan over the 8 ranking-relevant boundaries (uniform per wave)
        bool amb = false, flagme = false;
        float prev = m;
        #pragma unroll
        for (int t = 1; t <= TOPK; ++t) {
            const float vt = srt[wid][t];
            if (prev - vt < TAU) {
                amb = true;
                const float vb = 0.5f * (prev + vt);
                flagme = flagme || (fabsf(nl - vb) <= TAU);
            }
            prev = vt;
        }

        if (cnt < TOPK) out_idx[(size_t)grow * TOPK + cnt] = (float)lane;
        float ev = (cnt < TOPK) ? expf(nl - m) : 0.f;
        float s  = ev;
        #pragma unroll
        for (int off = 32; off >= 1; off >>= 1) s += __shfl_xor(s, off, 64);
        out_probs[(size_t)grow * EDIM + lane] = ev / s;

        if (amb) {
            // selective f64 repair: exact dots only for flagged experts
            unsigned long long mask = __ballot(flagme);
            double nld = (double)nl;
            const float* xr = x + (size_t)grow * CDIM;
            while (mask) {
                const int e = (int)__ffsll(mask) - 1;
                mask &= (mask - 1);
                double ar2 = 0.0, an = 0.0;
                const float* wrp = w_route + (size_t)e * CDIM;
                const float* wnp = w_noise + (size_t)e * CDIM;
                #pragma unroll
                for (int j = 0; j < 8; ++j) {
                    const int k = (j * 64 + lane) * 4;   // coalesced
                    const float4 xv = *(const float4*)(xr + k);
                    const float4 rv = *(const float4*)(wrp + k);
                    const float4 nq = *(const float4*)(wnp + k);
                    ar2 = fma((double)xv.x, (double)rv.x, ar2);
                    ar2 = fma((double)xv.y, (double)rv.y, ar2);
                    ar2 = fma((double)xv.z, (double)rv.z, ar2);
                    ar2 = fma((double)xv.w, (double)rv.w, ar2);
                    an  = fma((double)xv.x, (double)nq.x, an);
                    an  = fma((double)xv.y, (double)nq.y, an);
                    an  = fma((double)xv.z, (double)nq.z, an);
                    an  = fma((double)xv.w, (double)nq.w, an);
                }
                #pragma unroll
                for (int off = 32; off >= 1; off >>= 1) {
                    ar2 += __shfl_xor(ar2, off, 64);
                    an  += __shfl_xor(an, off, 64);
                }
                const double spd = fmax(an, 0.0) + log1p(exp(-fabs(an)));
                const double nve = (double)__shfl(nv, e, 64);
                const double v   = ar2 + nve * spd;
                if (lane == e) nld = v;
            }
            double workd = nld;
            int    rank2 = -1;
            double m2 = 0.0;
            #pragma unroll
            for (int t = 0; t < TOPK; ++t) {
                double bv = workd;
                int    bi = lane;
                #pragma unroll
                for (int off = 32; off >= 1; off >>= 1) {
                    const double ov = __shfl_xor(bv, off, 64);
                    const int    oi = __shfl_xor(bi, off, 64);
                    if (ov > bv || (ov == bv && oi < bi)) { bv = ov; bi = oi; }
                }
                if (t == 0) m2 = bv;
                if (lane == bi) {
                    rank2 = t;
                    workd = -INFINITY;
                    out_idx[(size_t)grow * TOPK + t] = (float)lane;
                }
            }
            float ev2 = (rank2 >= 0) ? expf((float)(nld - m2)) : 0.f;
            float s2  = ev2;
            #pragma unroll
            for (int off = 32; off >= 1; off >>= 1) s2 += __shfl_xor(s2, off, 64);
            out_probs[(size_t)grow * EDIM + lane] = ev2 / s2;
        }
    }
}

extern "C" void kernel_launch(void* const* d_in, const int* in_sizes, int n_in,
                              void* d_out, int out_size, void* d_ws, size_t ws_size,
                              hipStream_t stream)
{
    const float* x       = (const float*)d_in[0];
    const float* w_route = (const float*)d_in[1];
    const float* w_noise = (const float*)d_in[2];
    const float* noise   = (const float*)d_in[3];

    const int n_rows = in_sizes[0] / CDIM;                 // 16384
    float* out_probs = (float*)d_out;                      // (B,T,E) fp32
    float* out_idx   = out_probs + (size_t)n_rows * EDIM;  // (B,T,K) as fp32

    short* whi = (short*)d_ws;                             // 512 KB packed hi
    short* wlo = whi + (size_t)NOUT * CDIM;                // 512 KB packed lo

    hipLaunchKernelGGL(convert_w, dim3(NOUT * CDIM / (256 * 8)), dim3(256), 0, stream,
                       w_route, w_noise, whi, wlo);
    hipLaunchKernelGGL(router_fused, dim3(n_rows / BM), dim3(256), 0, stream,
                       x, whi, wlo, w_route, w_noise, noise, out_probs, out_idx);
}

// Round 2
// 249.157 us; speedup vs baseline: 1.1998x; 1.1998x over previous
//
#include <hip/hip_runtime.h>
#include <math.h>

// NoisyTopKRouter: B=4, T=4096, C=2048, E=64, K=8; rows = 16384.
// (1) convert_w: split w into hi/lo bf16 packed in MFMA-fragment order.
// (2) router_gemm: split-bf16 MFMA, K-split x4, x pre-split in LDS
//     (conflict-free pitch), B frags DIRECT from global (coalesced,
//     L2-resident, register double-buffered). Raw s_barrier + counted
//     waits (no vmcnt(0) drain in loop); x prefetch depth 2.
// (3) router_epilogue: rank-by-counting top-8 (no shfl chains), sparse
//     softmax, selective f64 near-tie repair (verified earlier rounds).

#define CDIM   2048
#define EDIM   64
#define NOUT   128
#define TOPK   8
#define NROWS  16384
#define BM     64
#define BK     32
#define KSPLIT 4
#define KQ     (CDIM / KSPLIT)   // 512
#define NIT    (KQ / BK)         // 16
#define TAU    1e-3f
#define XPS    72                // xsh pitch (shorts): 36 words -> 2-way reads (free)

typedef __attribute__((ext_vector_type(8))) short bf16x8;
typedef __attribute__((ext_vector_type(4))) float f32x4;

__device__ __forceinline__ void split8(const float4 a, const float4 b,
                                       bf16x8& h8, bf16x8& l8) {
    const float vv[8] = {a.x, a.y, a.z, a.w, b.x, b.y, b.z, b.w};
    #pragma unroll
    for (int j = 0; j < 8; ++j) {
        const __bf16 h = (__bf16)vv[j];
        const __bf16 l = (__bf16)(vv[j] - (float)h);
        h8[j] = __builtin_bit_cast(short, h);
        l8[j] = __builtin_bit_cast(short, l);
    }
}

// barrier WITHOUT vmcnt(0) drain: LDS writes made visible, global loads
// stay in flight (compiler still emits counted vmcnt for register uses).
__device__ __forceinline__ void block_sync() {
    asm volatile("s_waitcnt lgkmcnt(0)" ::: "memory");
    __builtin_amdgcn_s_barrier();
}

// ---- kernel 1: pack w into MFMA-fragment order, hi/lo bf16.
// slot s = (kc*8 + cg)*64 + lane holds w[col = cg*16 + (lane&15)]
//                                    [k = kc*32 + (lane>>4)*8 + j]
__global__ __launch_bounds__(256)
void convert_w(const float* __restrict__ wr, const float* __restrict__ wn,
               short* __restrict__ whi, short* __restrict__ wlo) {
    const int s    = (int)blockIdx.x * 256 + (int)threadIdx.x;  // 0..32767
    const int lane = s & 63;
    const int cg   = (s >> 6) & 7;
    const int kc   = s >> 9;
    const int col  = cg * 16 + (lane & 15);
    const int k0   = kc * 32 + (lane >> 4) * 8;
    const float* src = (col < EDIM ? wr + (size_t)col * CDIM
                                   : wn + (size_t)(col - EDIM) * CDIM) + k0;
    const float4 a = *(const float4*)src;
    const float4 b = *(const float4*)(src + 4);
    bf16x8 h8, l8; split8(a, b, h8, l8);
    *(bf16x8*)(whi + (size_t)s * 8) = h8;
    *(bf16x8*)(wlo + (size_t)s * 8) = l8;
}

// ---- kernel 2: split-bf16 MFMA GEMM, K-split x4 -> f32 partials
__global__ __launch_bounds__(256, 2)
void router_gemm(const float* __restrict__ x,
                 const short* __restrict__ whi,
                 const short* __restrict__ wlo,
                 float* __restrict__ part)
{
    __shared__ __align__(16) short xsh[2][BM][XPS];   // 18.4 KB

    const int tid  = (int)threadIdx.x;
    const int lane = tid & 63;
    const int wid  = tid >> 6;
    const int wr   = wid >> 1;          // row half (32 rows)
    const int wc   = wid & 1;           // col half (64 cols)
    const int l15  = lane & 15;
    const int q8   = (lane >> 4) * 8;
    const int q4   = (lane >> 4) * 4;
    const int qk   = (int)blockIdx.x & (KSPLIT - 1);
    const int row0 = ((int)blockIdx.x >> 2) * BM;

    const int srow = tid >> 2;          // 0..63
    const int skk  = (tid & 3) * 8;     // 0,8,16,24 (shorts)
    const float* xsrc = x + (size_t)(row0 + srow) * CDIM + qk * KQ + skk;

    f32x4 acc[2][4];
    #pragma unroll
    for (int mr = 0; mr < 2; ++mr)
        #pragma unroll
        for (int nc = 0; nc < 4; ++nc)
            acc[mr][nc] = (f32x4){0.f, 0.f, 0.f, 0.f};

    // B frags direct from global (packed, coalesced lane*16), dbl-buffered
    bf16x8 bh[2][4], bl[2][4];
    auto loadB = [&](int buf, int it) {
        const int base = ((qk * NIT + it) * 8 + wc * 4) * 512 + lane * 8;
        #pragma unroll
        for (int nc = 0; nc < 4; ++nc) {
            bh[buf][nc] = *(const bf16x8*)(whi + base + nc * 512);
            bl[buf][nc] = *(const bf16x8*)(wlo + base + nc * 512);
        }
    };

    // prologue: B(0) + x-chunk(0) staged + x-chunk(1) in regs (depth 2)
    loadB(0, 0);
    {
        const float4 a = *(const float4*)xsrc;
        const float4 b = *(const float4*)(xsrc + 4);
        bf16x8 h8, l8; split8(a, b, h8, l8);
        *(bf16x8*)&xsh[0][srow][skk]      = h8;
        *(bf16x8*)&xsh[0][srow][32 + skk] = l8;
    }
    float4 pfa[2], pfb[2];
    pfa[1] = *(const float4*)(xsrc + BK);
    pfb[1] = *(const float4*)(xsrc + BK + 4);
    block_sync();

    #pragma unroll 2
    for (int it = 0; it < NIT; ++it) {
        const int cur = it & 1;
        if (it + 1 < NIT) loadB(cur ^ 1, it + 1);   // B for next iter
        if (it + 2 < NIT) {                         // x two iters ahead
            pfa[cur] = *(const float4*)(xsrc + (it + 2) * BK);
            pfb[cur] = *(const float4*)(xsrc + (it + 2) * BK + 4);
        }
        bf16x8 ah[2], al[2];
        #pragma unroll
        for (int mr = 0; mr < 2; ++mr) {
            const short* ar = &xsh[cur][wr * 32 + mr * 16 + l15][0];
            ah[mr] = *(const bf16x8*)(ar + q8);
            al[mr] = *(const bf16x8*)(ar + 32 + q8);
        }
        #pragma unroll
        for (int mr = 0; mr < 2; ++mr)
            #pragma unroll
            for (int nc = 0; nc < 4; ++nc) {
                acc[mr][nc] = __builtin_amdgcn_mfma_f32_16x16x32_bf16(ah[mr], bh[cur][nc], acc[mr][nc], 0, 0, 0);
                acc[mr][nc] = __builtin_amdgcn_mfma_f32_16x16x32_bf16(al[mr], bh[cur][nc], acc[mr][nc], 0, 0, 0);
                acc[mr][nc] = __builtin_amdgcn_mfma_f32_16x16x32_bf16(ah[mr], bl[cur][nc], acc[mr][nc], 0, 0, 0);
            }
        if (it + 1 < NIT) {
            // x chunk it+1 was loaded at iter it-1 (or prologue): ~2 iters in flight
            bf16x8 h8, l8; split8(pfa[cur ^ 1], pfb[cur ^ 1], h8, l8);
            *(bf16x8*)&xsh[cur ^ 1][srow][skk]      = h8;
            *(bf16x8*)&xsh[cur ^ 1][srow][32 + skk] = l8;
            block_sync();
        }
    }

    // partial store (C/D layout: row = quad*4+reg, col = lane&15)
    float* dst = part + (size_t)qk * NROWS * NOUT;
    #pragma unroll
    for (int mr = 0; mr < 2; ++mr)
        #pragma unroll
        for (int nc = 0; nc < 4; ++nc)
            #pragma unroll
            for (int g = 0; g < 4; ++g)
                dst[(size_t)(row0 + wr * 32 + mr * 16 + q4 + g) * NOUT
                    + wc * 64 + nc * 16 + l15] = acc[mr][nc][g];
}

// ---- kernel 3: rank-by-counting epilogue; wave = one row
__global__ __launch_bounds__(256)
void router_epilogue(const float* __restrict__ x,
                     const float* __restrict__ w_route,
                     const float* __restrict__ w_noise,
                     const float* __restrict__ noise,
                     const float* __restrict__ part,
                     float* __restrict__ out_probs,
                     float* __restrict__ out_idx)
{
    __shared__ float vals[4][64];
    __shared__ float srt[4][64];

    const int tid  = (int)threadIdx.x;
    const int lane = tid & 63;   // lane == expert index
    const int wid  = tid >> 6;
    const int grow = (int)blockIdx.x * 4 + wid;
    const float* p0 = part;
    const float* p1 = part + (size_t)NROWS * NOUT;
    const float* p2 = part + (size_t)2 * NROWS * NOUT;
    const float* p3 = part + (size_t)3 * NROWS * NOUT;

    const size_t ro = (size_t)grow * NOUT;
    const float route = (p0[ro + lane] + p1[ro + lane])
                      + (p2[ro + lane] + p3[ro + lane]);
    const float nz    = (p0[ro + EDIM + lane] + p1[ro + EDIM + lane])
                      + (p2[ro + EDIM + lane] + p3[ro + EDIM + lane]);
    const float nv    = noise[(size_t)grow * EDIM + lane];
    const float sp = fmaxf(nz, 0.f) + log1pf(expf(-fabsf(nz)));
    const float nl = route + nv * sp;

    vals[wid][lane] = nl;
    __syncthreads();

    // rank = #{j better than me}; "better" = (v_j > v_i) or tie with j < i
    int cnt = 0;
    #pragma unroll
    for (int jq = 0; jq < 16; ++jq) {
        const float4 v = *(const float4*)&vals[wid][jq * 4];
        const int j0 = jq * 4;
        cnt += (v.x > nl || (v.x == nl && (j0 + 0) < lane));
        cnt += (v.y > nl || (v.y == nl && (j0 + 1) < lane));
        cnt += (v.z > nl || (v.z == nl && (j0 + 2) < lane));
        cnt += (v.w > nl || (v.w == nl && (j0 + 3) < lane));
    }
    srt[wid][cnt] = nl;   // ranks are a permutation of 0..63
    __syncthreads();

    const float m = srt[wid][0];
    // gap scan over the 8 ranking-relevant boundaries (uniform per wave)
    bool amb = false, flagme = false;
    float prev = m;
    #pragma unroll
    for (int t = 1; t <= TOPK; ++t) {
        const float vt = srt[wid][t];
        if (prev - vt < TAU) {
            amb = true;
            const float vb = 0.5f * (prev + vt);
            flagme = flagme || (fabsf(nl - vb) <= TAU);
        }
        prev = vt;
    }

    if (cnt < TOPK) out_idx[(size_t)grow * TOPK + cnt] = (float)lane;
    float ev = (cnt < TOPK) ? expf(nl - m) : 0.f;
    float s  = ev;
    #pragma unroll
    for (int off = 32; off >= 1; off >>= 1) s += __shfl_xor(s, off, 64);
    out_probs[(size_t)grow * EDIM + lane] = ev / s;

    if (amb) {
        // selective f64 repair: exact dots only for flagged experts
        unsigned long long mask = __ballot(flagme);
        double nld = (double)nl;
        const float* xr = x + (size_t)grow * CDIM;
        while (mask) {
            const int e = (int)__ffsll(mask) - 1;
            mask &= (mask - 1);
            double ar = 0.0, an = 0.0;
            const float* wrp = w_route + (size_t)e * CDIM;
            const float* wnp = w_noise + (size_t)e * CDIM;
            #pragma unroll
            for (int j = 0; j < 8; ++j) {
                const int k = (j * 64 + lane) * 4;   // coalesced
                const float4 xv = *(const float4*)(xr + k);
                const float4 rv = *(const float4*)(wrp + k);
                const float4 nq = *(const float4*)(wnp + k);
                ar = fma((double)xv.x, (double)rv.x, ar);
                ar = fma((double)xv.y, (double)rv.y, ar);
                ar = fma((double)xv.z, (double)rv.z, ar);
                ar = fma((double)xv.w, (double)rv.w, ar);
                an = fma((double)xv.x, (double)nq.x, an);
                an = fma((double)xv.y, (double)nq.y, an);
                an = fma((double)xv.z, (double)nq.z, an);
                an = fma((double)xv.w, (double)nq.w, an);
            }
            #pragma unroll
            for (int off = 32; off >= 1; off >>= 1) {
                ar += __shfl_xor(ar, off, 64);
                an += __shfl_xor(an, off, 64);
            }
            const double spd = fmax(an, 0.0) + log1p(exp(-fabs(an)));
            const double nve = (double)__shfl(nv, e, 64);
            const double v   = ar + nve * spd;
            if (lane == e) nld = v;
        }
        double workd = nld;
        int    rank2 = -1;
        double m2 = 0.0;
        #pragma unroll
        for (int t = 0; t < TOPK; ++t) {
            double bv = workd;
            int    bi = lane;
            #pragma unroll
            for (int off = 32; off >= 1; off >>= 1) {
                const double ov = __shfl_xor(bv, off, 64);
                const int    oi = __shfl_xor(bi, off, 64);
                if (ov > bv || (ov == bv && oi < bi)) { bv = ov; bi = oi; }
            }
            if (t == 0) m2 = bv;
            if (lane == bi) {
                rank2 = t;
                workd = -INFINITY;
                out_idx[(size_t)grow * TOPK + t] = (float)lane;
            }
        }
        float ev2 = (rank2 >= 0) ? expf((float)(nld - m2)) : 0.f;
        float s2  = ev2;
        #pragma unroll
        for (int off = 32; off >= 1; off >>= 1) s2 += __shfl_xor(s2, off, 64);
        out_probs[(size_t)grow * EDIM + lane] = ev2 / s2;
    }
}

extern "C" void kernel_launch(void* const* d_in, const int* in_sizes, int n_in,
                              void* d_out, int out_size, void* d_ws, size_t ws_size,
                              hipStream_t stream)
{
    const float* x       = (const float*)d_in[0];
    const float* w_route = (const float*)d_in[1];
    const float* w_noise = (const float*)d_in[2];
    const float* noise   = (const float*)d_in[3];

    const int n_rows = in_sizes[0] / CDIM;                 // 16384
    float* out_probs = (float*)d_out;                      // (B,T,E) fp32
    float* out_idx   = out_probs + (size_t)n_rows * EDIM;  // (B,T,K) as fp32

    short* whi  = (short*)d_ws;                            // 512 KB packed hi
    short* wlo  = whi + (size_t)NOUT * CDIM;               // 512 KB packed lo
    float* part = (float*)((char*)d_ws + 2u * 1024u * 1024u); // 4 x 16384 x 128 f32

    hipLaunchKernelGGL(convert_w, dim3(NOUT * CDIM / (256 * 8)), dim3(256), 0, stream,
                       w_route, w_noise, whi, wlo);
    hipLaunchKernelGGL(router_gemm, dim3((n_rows / BM) * KSPLIT), dim3(256), 0, stream,
                       x, whi, wlo, part);
    hipLaunchKernelGGL(router_epilogue, dim3(n_rows / 4), dim3(256), 0, stream,
                       x, w_route, w_noise, noise, part, out_probs, out_idx);
}

// Round 3
// 243.426 us; speedup vs baseline: 1.2281x; 1.0235x over previous
//
#include <hip/hip_runtime.h>
#include <math.h>

// NoisyTopKRouter: B=4, T=4096, C=2048, E=64, K=8; rows = 16384.
// (1) convert_w: split w into hi/lo bf16 packed in MFMA-fragment order.
// (2) router_gemm: split-bf16 MFMA, K-split x4, x pre-split in LDS
//     (conflict-free pitch), B frags DIRECT from global (L2-resident,
//     single-buffered regs). Occupancy-first: launch_bounds(256,4) ->
//     VGPR<=128 -> 4 blocks/CU = 16 waves/CU; TLP hides latency.
//     Counted-wait barrier (no vmcnt(0) drain in loop).
// (3) router_epilogue: rank-by-counting top-8; wave-private LDS sync
//     (no block barriers); sparse softmax, selective f64 tie repair.

#define CDIM   2048
#define EDIM   64
#define NOUT   128
#define TOPK   8
#define NROWS  16384
#define BM     64
#define BK     32
#define KSPLIT 4
#define KQ     (CDIM / KSPLIT)   // 512
#define NIT    (KQ / BK)         // 16
#define TAU    1e-3f
#define XPS    72                // xsh pitch (shorts): 36 words -> 2-way reads (free)

typedef __attribute__((ext_vector_type(8))) short bf16x8;
typedef __attribute__((ext_vector_type(4))) float f32x4;

__device__ __forceinline__ void split8(const float4 a, const float4 b,
                                       bf16x8& h8, bf16x8& l8) {
    const float vv[8] = {a.x, a.y, a.z, a.w, b.x, b.y, b.z, b.w};
    #pragma unroll
    for (int j = 0; j < 8; ++j) {
        const __bf16 h = (__bf16)vv[j];
        const __bf16 l = (__bf16)(vv[j] - (float)h);
        h8[j] = __builtin_bit_cast(short, h);
        l8[j] = __builtin_bit_cast(short, l);
    }
}

// barrier WITHOUT vmcnt(0) drain: LDS writes made visible, global loads
// stay in flight (compiler still emits counted vmcnt for register uses).
__device__ __forceinline__ void block_sync() {
    asm volatile("s_waitcnt lgkmcnt(0)" ::: "memory");
    __builtin_amdgcn_s_barrier();
}

// wave-private LDS visibility: DS pipe is in-order per wave, lanes are
// lockstep -> a counted-wait is enough, no s_barrier needed.
__device__ __forceinline__ void wave_lds_sync() {
    asm volatile("s_waitcnt lgkmcnt(0)" ::: "memory");
}

// ---- kernel 1: pack w into MFMA-fragment order, hi/lo bf16.
// slot s = (kc*8 + cg)*64 + lane holds w[col = cg*16 + (lane&15)]
//                                    [k = kc*32 + (lane>>4)*8 + j]
__global__ __launch_bounds__(256)
void convert_w(const float* __restrict__ wr, const float* __restrict__ wn,
               short* __restrict__ whi, short* __restrict__ wlo) {
    const int s    = (int)blockIdx.x * 256 + (int)threadIdx.x;  // 0..32767
    const int lane = s & 63;
    const int cg   = (s >> 6) & 7;
    const int kc   = s >> 9;
    const int col  = cg * 16 + (lane & 15);
    const int k0   = kc * 32 + (lane >> 4) * 8;
    const float* src = (col < EDIM ? wr + (size_t)col * CDIM
                                   : wn + (size_t)(col - EDIM) * CDIM) + k0;
    const float4 a = *(const float4*)src;
    const float4 b = *(const float4*)(src + 4);
    bf16x8 h8, l8; split8(a, b, h8, l8);
    *(bf16x8*)(whi + (size_t)s * 8) = h8;
    *(bf16x8*)(wlo + (size_t)s * 8) = l8;
}

// ---- kernel 2: split-bf16 MFMA GEMM, K-split x4 -> f32 partials
__global__ __launch_bounds__(256, 4)
void router_gemm(const float* __restrict__ x,
                 const short* __restrict__ whi,
                 const short* __restrict__ wlo,
                 float* __restrict__ part)
{
    __shared__ __align__(16) short xsh[2][BM][XPS];   // 18.4 KB

    const int tid  = (int)threadIdx.x;
    const int lane = tid & 63;
    const int wid  = tid >> 6;
    const int wr   = wid >> 1;          // row half (32 rows)
    const int wc   = wid & 1;           // col half (64 cols)
    const int l15  = lane & 15;
    const int q8   = (lane >> 4) * 8;
    const int q4   = (lane >> 4) * 4;
    const int qk   = (int)blockIdx.x & (KSPLIT - 1);
    const int row0 = ((int)blockIdx.x >> 2) * BM;

    const int srow = tid >> 2;          // 0..63
    const int skk  = (tid & 3) * 8;     // 0,8,16,24 (shorts)
    const float* xsrc = x + (size_t)(row0 + srow) * CDIM + qk * KQ + skk;

    f32x4 acc[2][4];
    #pragma unroll
    for (int mr = 0; mr < 2; ++mr)
        #pragma unroll
        for (int nc = 0; nc < 4; ++nc)
            acc[mr][nc] = (f32x4){0.f, 0.f, 0.f, 0.f};

    // B frags direct from global (packed, coalesced lane*16), SINGLE buffer
    // (issued at iter top; MFMA's counted vmcnt waits only on these, the
    // later-issued x loads stay in flight across the wait and the barrier)
    bf16x8 bh[4], bl[4];
    auto loadB = [&](int it) {
        const int base = ((qk * NIT + it) * 8 + wc * 4) * 512 + lane * 8;
        #pragma unroll
        for (int nc = 0; nc < 4; ++nc) {
            bh[nc] = *(const bf16x8*)(whi + base + nc * 512);
            bl[nc] = *(const bf16x8*)(wlo + base + nc * 512);
        }
    };

    // prologue: x-chunk(0) staged + x-chunk(1) in regs (depth 2)
    {
        const float4 a = *(const float4*)xsrc;
        const float4 b = *(const float4*)(xsrc + 4);
        bf16x8 h8, l8; split8(a, b, h8, l8);
        *(bf16x8*)&xsh[0][srow][skk]      = h8;
        *(bf16x8*)&xsh[0][srow][32 + skk] = l8;
    }
    float4 pfa[2], pfb[2];
    pfa[1] = *(const float4*)(xsrc + BK);
    pfb[1] = *(const float4*)(xsrc + BK + 4);
    block_sync();

    #pragma unroll 2
    for (int it = 0; it < NIT; ++it) {
        const int cur = it & 1;
        loadB(it);                                  // L2-resident, this iter
        if (it + 2 < NIT) {                         // x two iters ahead (HBM)
            pfa[cur] = *(const float4*)(xsrc + (it + 2) * BK);
            pfb[cur] = *(const float4*)(xsrc + (it + 2) * BK + 4);
        }
        bf16x8 ah[2], al[2];
        #pragma unroll
        for (int mr = 0; mr < 2; ++mr) {
            const short* ar = &xsh[cur][wr * 32 + mr * 16 + l15][0];
            ah[mr] = *(const bf16x8*)(ar + q8);
            al[mr] = *(const bf16x8*)(ar + 32 + q8);
        }
        #pragma unroll
        for (int mr = 0; mr < 2; ++mr)
            #pragma unroll
            for (int nc = 0; nc < 4; ++nc) {
                acc[mr][nc] = __builtin_amdgcn_mfma_f32_16x16x32_bf16(ah[mr], bh[nc], acc[mr][nc], 0, 0, 0);
                acc[mr][nc] = __builtin_amdgcn_mfma_f32_16x16x32_bf16(al[mr], bh[nc], acc[mr][nc], 0, 0, 0);
                acc[mr][nc] = __builtin_amdgcn_mfma_f32_16x16x32_bf16(ah[mr], bl[nc], acc[mr][nc], 0, 0, 0);
            }
        if (it + 1 < NIT) {
            // x chunk it+1 was issued at iter it-1 (or prologue): ~2 iters in flight
            bf16x8 h8, l8; split8(pfa[cur ^ 1], pfb[cur ^ 1], h8, l8);
            *(bf16x8*)&xsh[cur ^ 1][srow][skk]      = h8;
            *(bf16x8*)&xsh[cur ^ 1][srow][32 + skk] = l8;
            block_sync();
        }
    }

    // partial store (C/D layout: row = quad*4+reg, col = lane&15)
    float* dst = part + (size_t)qk * NROWS * NOUT;
    #pragma unroll
    for (int mr = 0; mr < 2; ++mr)
        #pragma unroll
        for (int nc = 0; nc < 4; ++nc)
            #pragma unroll
            for (int g = 0; g < 4; ++g)
                dst[(size_t)(row0 + wr * 32 + mr * 16 + q4 + g) * NOUT
                    + wc * 64 + nc * 16 + l15] = acc[mr][nc][g];
}

// ---- kernel 3: rank-by-counting epilogue; wave = one row
__global__ __launch_bounds__(256, 4)
void router_epilogue(const float* __restrict__ x,
                     const float* __restrict__ w_route,
                     const float* __restrict__ w_noise,
                     const float* __restrict__ noise,
                     const float* __restrict__ part,
                     float* __restrict__ out_probs,
                     float* __restrict__ out_idx)
{
    __shared__ float vals[4][64];
    __shared__ float srt[4][64];

    const int tid  = (int)threadIdx.x;
    const int lane = tid & 63;   // lane == expert index
    const int wid  = tid >> 6;
    const int grow = (int)blockIdx.x * 4 + wid;
    const float* p0 = part;
    const float* p1 = part + (size_t)NROWS * NOUT;
    const float* p2 = part + (size_t)2 * NROWS * NOUT;
    const float* p3 = part + (size_t)3 * NROWS * NOUT;

    const size_t ro = (size_t)grow * NOUT;
    const float route = (p0[ro + lane] + p1[ro + lane])
                      + (p2[ro + lane] + p3[ro + lane]);
    const float nz    = (p0[ro + EDIM + lane] + p1[ro + EDIM + lane])
                      + (p2[ro + EDIM + lane] + p3[ro + EDIM + lane]);
    const float nv    = noise[(size_t)grow * EDIM + lane];
    const float sp = fmaxf(nz, 0.f) + log1pf(expf(-fabsf(nz)));
    const float nl = route + nv * sp;

    vals[wid][lane] = nl;        // wave-private slice: no block barrier
    wave_lds_sync();

    // rank = #{j better than me}; "better" = (v_j > v_i) or tie with j < i
    int cnt = 0;
    #pragma unroll
    for (int jq = 0; jq < 16; ++jq) {
        const float4 v = *(const float4*)&vals[wid][jq * 4];
        const int j0 = jq * 4;
        cnt += (v.x > nl || (v.x == nl && (j0 + 0) < lane));
        cnt += (v.y > nl || (v.y == nl && (j0 + 1) < lane));
        cnt += (v.z > nl || (v.z == nl && (j0 + 2) < lane));
        cnt += (v.w > nl || (v.w == nl && (j0 + 3) < lane));
    }
    srt[wid][cnt] = nl;   // ranks are a permutation of 0..63
    wave_lds_sync();

    const float m = srt[wid][0];
    // gap scan over the 8 ranking-relevant boundaries (uniform per wave)
    bool amb = false, flagme = false;
    float prev = m;
    #pragma unroll
    for (int t = 1; t <= TOPK; ++t) {
        const float vt = srt[wid][t];
        if (prev - vt < TAU) {
            amb = true;
            const float vb = 0.5f * (prev + vt);
            flagme = flagme || (fabsf(nl - vb) <= TAU);
        }
        prev = vt;
    }

    if (cnt < TOPK) out_idx[(size_t)grow * TOPK + cnt] = (float)lane;
    float ev = (cnt < TOPK) ? expf(nl - m) : 0.f;
    float s  = ev;
    #pragma unroll
    for (int off = 32; off >= 1; off >>= 1) s += __shfl_xor(s, off, 64);
    out_probs[(size_t)grow * EDIM + lane] = ev / s;

    if (amb) {
        // selective f64 repair: exact dots only for flagged experts
        unsigned long long mask = __ballot(flagme);
        double nld = (double)nl;
        const float* xr = x + (size_t)grow * CDIM;
        while (mask) {
            const int e = (int)__ffsll(mask) - 1;
            mask &= (mask - 1);
            double ar = 0.0, an = 0.0;
            const float* wrp = w_route + (size_t)e * CDIM;
            const float* wnp = w_noise + (size_t)e * CDIM;
            #pragma unroll
            for (int j = 0; j < 8; ++j) {
                const int k = (j * 64 + lane) * 4;   // coalesced
                const float4 xv = *(const float4*)(xr + k);
                const float4 rv = *(const float4*)(wrp + k);
                const float4 nq = *(const float4*)(wnp + k);
                ar = fma((double)xv.x, (double)rv.x, ar);
                ar = fma((double)xv.y, (double)rv.y, ar);
                ar = fma((double)xv.z, (double)rv.z, ar);
                ar = fma((double)xv.w, (double)rv.w, ar);
                an = fma((double)xv.x, (double)nq.x, an);
                an = fma((double)xv.y, (double)nq.y, an);
                an = fma((double)xv.z, (double)nq.z, an);
                an = fma((double)xv.w, (double)nq.w, an);
            }
            #pragma unroll
            for (int off = 32; off >= 1; off >>= 1) {
                ar += __shfl_xor(ar, off, 64);
                an += __shfl_xor(an, off, 64);
            }
            const double spd = fmax(an, 0.0) + log1p(exp(-fabs(an)));
            const double nve = (double)__shfl(nv, e, 64);
            const double v   = ar + nve * spd;
            if (lane == e) nld = v;
        }
        double workd = nld;
        int    rank2 = -1;
        double m2 = 0.0;
        #pragma unroll
        for (int t = 0; t < TOPK; ++t) {
            double bv = workd;
            int    bi = lane;
            #pragma unroll
            for (int off = 32; off >= 1; off >>= 1) {
                const double ov = __shfl_xor(bv, off, 64);
                const int    oi = __shfl_xor(bi, off, 64);
                if (ov > bv || (ov == bv && oi < bi)) { bv = ov; bi = oi; }
            }
            if (t == 0) m2 = bv;
            if (lane == bi) {
                rank2 = t;
                workd = -INFINITY;
                out_idx[(size_t)grow * TOPK + t] = (float)lane;
            }
        }
        float ev2 = (rank2 >= 0) ? expf((float)(nld - m2)) : 0.f;
        float s2  = ev2;
        #pragma unroll
        for (int off = 32; off >= 1; off >>= 1) s2 += __shfl_xor(s2, off, 64);
        out_probs[(size_t)grow * EDIM + lane] = ev2 / s2;
    }
}

extern "C" void kernel_launch(void* const* d_in, const int* in_sizes, int n_in,
                              void* d_out, int out_size, void* d_ws, size_t ws_size,
                              hipStream_t stream)
{
    const float* x       = (const float*)d_in[0];
    const float* w_route = (const float*)d_in[1];
    const float* w_noise = (const float*)d_in[2];
    const float* noise   = (const float*)d_in[3];

    const int n_rows = in_sizes[0] / CDIM;                 // 16384
    float* out_probs = (float*)d_out;                      // (B,T,E) fp32
    float* out_idx   = out_probs + (size_t)n_rows * EDIM;  // (B,T,K) as fp32

    short* whi  = (short*)d_ws;                            // 512 KB packed hi
    short* wlo  = whi + (size_t)NOUT * CDIM;               // 512 KB packed lo
    float* part = (float*)((char*)d_ws + 2u * 1024u * 1024u); // 4 x 16384 x 128 f32

    hipLaunchKernelGGL(convert_w, dim3(NOUT * CDIM / (256 * 8)), dim3(256), 0, stream,
                       w_route, w_noise, whi, wlo);
    hipLaunchKernelGGL(router_gemm, dim3((n_rows / BM) * KSPLIT), dim3(256), 0, stream,
                       x, whi, wlo, part);
    hipLaunchKernelGGL(router_epilogue, dim3(n_rows / 4), dim3(256), 0, stream,
                       x, w_route, w_noise, noise, part, out_probs, out_idx);
}